// Round 10
// baseline (22.060 us; speedup 1.0000x reference)
//
#include <hip/hip_runtime.h>
#include <math.h>

// Problem constants (match reference)
#define BB 32
#define SS 52
#define AA 3
#define CC 80
// per-anchor pred row = C+5 = 85 floats; per-cell = 255 floats

constexpr int N_CELL = BB * SS * SS;        // 86528
constexpr int N_ANCH = N_CELL * AA;         // 259584 == 1014 * 256 exactly
constexpr int BLOCK  = 256;
constexpr int NBLK   = N_ANCH / BLOCK;      // 1014
constexpr int NBUCK  = 16;                  // accumulation buckets

// ws layout (floats), everything on its own 128B line to spread atomic traffic:
//   acc line (b,k):  ws[(b*5 + k) * 32]          b in [0,16), k in [0,5)  -> lines 0..79
//   sub-ticket b:    ((unsigned*)(ws + 2560 + b*32))[0]                   -> lines 80..95
//   master ticket:   ((unsigned*)(ws + 3072))[0]                          -> line 96
// memset covers bytes [0, 12544) each call.
// k: 0 sum obj_f, 1 sum bce*noobj, 2 sum ce*obj, 3 sum sq*obj, 4 sum objterm*obj

typedef float f4v __attribute__((ext_vector_type(4), aligned(4)));

__device__ __forceinline__ float fast_rcp(float x) {
    return __builtin_amdgcn_rcpf(x);
}

__global__ __launch_bounds__(BLOCK) void yolo_fused(
    const float* __restrict__ target,
    const float* __restrict__ pred,
    const float* __restrict__ anchors,
    float* __restrict__ ws,
    float* __restrict__ out)
{
    const int tid  = threadIdx.x;
    const int n    = blockIdx.x * BLOCK + tid;   // exact grid, no bounds check
    const int lane = tid & 63;
    const int grp  = lane >> 4;                  // quarter-wave group 0..3
    const int l16  = lane & 15;

    const int cell = n / 3;
    const int a    = n - cell * 3;
    const int poff = cell * 255 + a * 85;

    // ---- stage this block's 6KB target slab + anchors into LDS (coalesced) ----
    __shared__ float ldsT[BLOCK * 6];            // 1536 floats = 384 float4
    __shared__ float ldsA[6];
    __shared__ int   s_fin;
    {
        const float4* tsrc = reinterpret_cast<const float4*>(target + (size_t)blockIdx.x * (BLOCK * 6));
        float4* tdst = reinterpret_cast<float4*>(ldsT);
        tdst[tid] = tsrc[tid];
        if (tid < 128) tdst[256 + tid] = tsrc[256 + tid];
        if (tid < 6)   ldsA[tid] = anchors[tid];
        if (tid == 0)  s_fin = 0;
    }
    __syncthreads();

    // ---- per-thread loads ----
    const float* tr = ldsT + tid * 6;
    const float2 t01 = *reinterpret_cast<const float2*>(tr);
    const float2 t23 = *reinterpret_cast<const float2*>(tr + 2);
    const float2 t45 = *reinterpret_cast<const float2*>(tr + 4);
    const f4v   pq = *reinterpret_cast<const f4v*>(pred + poff);  // p0..p3
    const float p4 = pred[poff + 4];
    const float p0 = pq.x, p1 = pq.y, p2 = pq.z, p3 = pq.w;
    const float aw = ldsA[a * 2 + 0];
    const float ah = ldsA[a * 2 + 1];

    const bool isobj   = (t01.x != 0.0f);
    const int  label_l = isobj ? (int)t45.y : 0;

    // ---- peel CE iteration 0: issue its gather before the box/IoU math ----
    unsigned long long m = __ballot(isobj);
    unsigned long long m2 = m;
    int b0 = -1, b1 = -1, b2 = -1, b3 = -1;
    if (m2) { b0 = __ffsll(m2) - 1; m2 &= m2 - 1; }
    if (m2) { b1 = __ffsll(m2) - 1; m2 &= m2 - 1; }
    if (m2) { b2 = __ffsll(m2) - 1; m2 &= m2 - 1; }
    if (m2) { b3 = __ffsll(m2) - 1; m2 &= m2 - 1; }
    int  src0 = (grp == 0) ? b0 : (grp == 1) ? b1 : (grp == 2) ? b2 : b3;
    bool act0 = (src0 >= 0);
    int  s0   = act0 ? src0 : 0;
    int  offu0  = __shfl(poff, s0, 64) + 5;
    int  label0 = __shfl(label_l, s0, 64);
    const float* cl0 = pred + offu0;
    float w0 = 0.f, w1 = 0.f, w2 = 0.f, w3 = 0.f, w4 = 0.f;
    if (act0) {
        w0 = cl0[l16];      w1 = cl0[l16 + 16]; w2 = cl0[l16 + 32];
        w3 = cl0[l16 + 48]; w4 = cl0[l16 + 64];
    }

    float s_obj = 0.f, s_bce = 0.f, s_ce = 0.f, s_sq = 0.f, s_objt = 0.f;

    // ---- per-anchor math (native transcendentals; abs tolerance 0.49) ----
    if (!isobj) {
        s_bce = fmaxf(p0, 0.0f) + __logf(1.0f + __expf(-fabsf(p0)));
    } else {
        s_obj = 1.0f;

        float px = fast_rcp(1.0f + __expf(-p1));   // sigmoid
        float py = fast_rcp(1.0f + __expf(-p2));
        float tx = t01.y, ty = t23.x;
        float tw = __logf(1e-16f + t23.y * fast_rcp(aw));
        float th = __logf(1e-16f + t45.x * fast_rcp(ah));
        float dx = tx - px, dy = ty - py, dw = tw - p3, dh = th - p4;
        s_sq = dx * dx + dy * dy + dw * dw + dh * dh;

        // objectness MSE vs IoU (faithful reference quirk)
        float bw = __expf(p3) * aw;
        float bh = __expf(p4) * ah;
        float b1x1 = px - bw * 0.5f, b1x2 = px + bw * 0.5f;
        float b1y1 = py - bh * 0.5f, b1y2 = py + bh * 0.5f;
        float b2x1 = tx - tw * 0.5f, b2x2 = tx + tw * 0.5f;
        float b2y1 = ty - th * 0.5f, b2y2 = ty + th * 0.5f;
        float iw = fmaxf(fminf(b1x2, b2x2) - fmaxf(b1x1, b2x1), 0.0f);
        float ih = fmaxf(fminf(b1y2, b2y2) - fmaxf(b1y1, b2y1), 0.0f);
        float inter = iw * ih;
        float a1 = fabsf((b1x2 - b1x1) * (b1y2 - b1y1));
        float a2 = fabsf((b2x2 - b2x1) * (b2y2 - b2y1));
        float iou = inter * fast_rcp(a1 + a2 - inter + 1e-6f);
        float d = iou - p0;
        s_objt = d * d;
    }

    // ---- finish CE iteration 0 ----
    if (m) {
        float mx = fmaxf(fmaxf(fmaxf(w0, w1), fmaxf(w2, w3)), w4);
        #pragma unroll
        for (int o = 8; o > 0; o >>= 1) mx = fmaxf(mx, __shfl_xor(mx, o, 16));

        float se = __expf(w0 - mx) + __expf(w1 - mx) + __expf(w2 - mx)
                 + __expf(w3 - mx) + __expf(w4 - mx);
        #pragma unroll
        for (int o = 8; o > 0; o >>= 1) se += __shfl_xor(se, o, 16);

        int r  = label0 >> 4;
        float cand = (r == 0) ? w0 : (r == 1) ? w1 : (r == 2) ? w2
                   : (r == 3) ? w3 : w4;
        float cll  = __shfl(cand, (grp << 4) + (label0 & 15), 64);

        if (act0 && l16 == 0) s_ce += (mx + __logf(se)) - cll;
    }

    // ---- remaining CE iterations (~20% of waves) ----
    while (m2) {
        int c0 = -1, c1 = -1, c2 = -1, c3 = -1;
        if (m2) { c0 = __ffsll(m2) - 1; m2 &= m2 - 1; }
        if (m2) { c1 = __ffsll(m2) - 1; m2 &= m2 - 1; }
        if (m2) { c2 = __ffsll(m2) - 1; m2 &= m2 - 1; }
        if (m2) { c3 = __ffsll(m2) - 1; m2 &= m2 - 1; }
        int src = (grp == 0) ? c0 : (grp == 1) ? c1 : (grp == 2) ? c2 : c3;
        bool active = (src >= 0);
        int s = active ? src : 0;
        int offu  = __shfl(poff, s, 64) + 5;
        int label = __shfl(label_l, s, 64);
        const float* cl = pred + offu;

        float v0 = 0.f, v1 = 0.f, v2 = 0.f, v3 = 0.f, v4 = 0.f;
        if (active) {
            v0 = cl[l16];      v1 = cl[l16 + 16]; v2 = cl[l16 + 32];
            v3 = cl[l16 + 48]; v4 = cl[l16 + 64];
        }

        float mx = fmaxf(fmaxf(fmaxf(v0, v1), fmaxf(v2, v3)), v4);
        #pragma unroll
        for (int o = 8; o > 0; o >>= 1) mx = fmaxf(mx, __shfl_xor(mx, o, 16));

        float se = __expf(v0 - mx) + __expf(v1 - mx) + __expf(v2 - mx)
                 + __expf(v3 - mx) + __expf(v4 - mx);
        #pragma unroll
        for (int o = 8; o > 0; o >>= 1) se += __shfl_xor(se, o, 16);

        int r  = label >> 4;
        float cand = (r == 0) ? v0 : (r == 1) ? v1 : (r == 2) ? v2
                   : (r == 3) ? v3 : v4;
        float cll  = __shfl(cand, (grp << 4) + (label & 15), 64);

        if (active && l16 == 0) s_ce += (mx + __logf(se)) - cll;
    }

    // ---- wave-64 reduction ----
    #pragma unroll
    for (int off = 32; off > 0; off >>= 1) {
        s_obj  += __shfl_down(s_obj,  off, 64);
        s_bce  += __shfl_down(s_bce,  off, 64);
        s_sq   += __shfl_down(s_sq,   off, 64);
        s_objt += __shfl_down(s_objt, off, 64);
    }
    s_ce += __shfl_down(s_ce, 32, 64);
    s_ce += __shfl_down(s_ce, 16, 64);

    // ---- block reduction through LDS ----
    __shared__ float red[4][5];
    int wave = tid >> 6;
    if ((tid & 63) == 0) {
        red[wave][0] = s_obj; red[wave][1] = s_bce; red[wave][2] = s_ce;
        red[wave][3] = s_sq;  red[wave][4] = s_objt;
    }
    __syncthreads();

    // ---- cross-block accumulation: device-scope atomics ONLY (no fences,
    // no threadfence -> no L2 writeback storm, unlike R4). Each (bucket,
    // counter) pair sits on its own 128B line: <=64 serialized adds/line. ----
    const int bkt = blockIdx.x & (NBUCK - 1);
    if (tid < 5) {
        float v = red[0][tid] + red[1][tid] + red[2][tid] + red[3][tid];
        atomicAdd(ws + (bkt * 5 + tid) * 32, v);
    }
    // order: this wave's accumulator RMWs must COMPLETE before ticketing.
    // s_waitcnt drains outstanding vmem without any cache maintenance.
    asm volatile("s_waitcnt vmcnt(0)" ::: "memory");

    if (tid == 0) {
        // hierarchical completion tickets: 16 sub (<=64 adds each) -> 1 master
        unsigned int quota = (bkt < 6) ? 64u : 63u;   // 1014 = 6*64 + 10*63
        unsigned int* sub    = reinterpret_cast<unsigned int*>(ws + 2560 + bkt * 32);
        unsigned int* master = reinterpret_cast<unsigned int*>(ws + 3072);
        unsigned int old = atomicAdd(sub, 1u);
        if (old == quota - 1u) {
            unsigned int old2 = atomicAdd(master, 1u);
            if (old2 == (unsigned int)(NBUCK - 1)) s_fin = 1;
        }
    }
    __syncthreads();

    // ---- unique finalizer block: read accumulators via agent-scope atomic
    // loads (coherence point -> always current), emit the scalar ----
    if (s_fin) {
        __shared__ float vals[80];
        if (tid < 80) {
            vals[tid] = __hip_atomic_load(ws + tid * 32, __ATOMIC_RELAXED,
                                          __HIP_MEMORY_SCOPE_AGENT);
        }
        __syncthreads();
        if (tid == 0) {
            float t[5] = {0.f, 0.f, 0.f, 0.f, 0.f};
            #pragma unroll
            for (int b = 0; b < NBUCK; ++b) {
                #pragma unroll
                for (int k = 0; k < 5; ++k) t[k] += vals[b * 5 + k];
            }
            float n_obj   = fmaxf(t[0], 1.0f);
            float n_noobj = fmaxf((float)N_ANCH - t[0], 1.0f);
            float noobjloss = t[1] / n_noobj;
            float classloss = t[2] / n_obj;
            float boxloss   = t[3] / (4.0f * n_obj);
            float objloss   = t[4] / n_obj;
            // L_NOOBJ*noobj + L_CLASS*class + L_BOX*box + L_OBJ*obj
            out[0] = 10.0f * noobjloss + 1.0f * classloss
                   + 10.0f * boxloss + 1.0f * objloss;
        }
    }
}

extern "C" void kernel_launch(void* const* d_in, const int* in_sizes, int n_in,
                              void* d_out, int out_size, void* d_ws, size_t ws_size,
                              hipStream_t stream) {
    const float* target  = (const float*)d_in[0];
    const float* pred    = (const float*)d_in[1];
    const float* anchors = (const float*)d_in[2];
    float* out = (float*)d_out;
    float* ws  = (float*)d_ws;

    // zero accumulators + tickets each call (graph-capture legal, deterministic)
    hipMemsetAsync(ws, 0, 12544, stream);

    hipLaunchKernelGGL(yolo_fused, dim3(NBLK), dim3(BLOCK), 0, stream,
                       target, pred, anchors, ws, out);
}

// Round 11
// 17.423 us; speedup vs baseline: 1.2662x; 1.2662x over previous
//
#include <hip/hip_runtime.h>
#include <math.h>

// Problem constants (match reference)
#define BB 32
#define SS 52
#define AA 3
#define CC 80
// per-anchor pred row = C+5 = 85 floats; per-cell = 255 floats

constexpr int N_CELL = BB * SS * SS;        // 86528
constexpr int N_ANCH = N_CELL * AA;         // 259584 == 1014 * 256 exactly
constexpr int BLOCK  = 256;
constexpr int NBLK   = N_ANCH / BLOCK;      // 1014
constexpr int WSCOL  = 1024;                // padded column stride for partials

typedef float f4v __attribute__((ext_vector_type(4), aligned(4)));

__device__ __forceinline__ float fast_rcp(float x) {
    return __builtin_amdgcn_rcpf(x);
}

// ws layout (floats), column-major: ws[k*WSCOL + blk], k = 0..2
// k: 0 sum obj_f, 1 sum bce*noobj, 2 sum (ce + 2.5*sq + objt)*obj
// (classloss + 10*boxloss + objloss = (ce + 2.5*sq + objt)/n_obj, shared divisor)

__global__ __launch_bounds__(BLOCK) void yolo_main(
    const float* __restrict__ target,
    const float* __restrict__ pred,
    const float* __restrict__ anchors,
    float* __restrict__ ws)
{
    const int tid  = threadIdx.x;
    const int n    = blockIdx.x * BLOCK + tid;   // exact grid, no bounds check
    const int lane = tid & 63;
    const int grp  = lane >> 4;                  // quarter-wave group 0..3
    const int l16  = lane & 15;

    const int cell = n / 3;
    const int a    = n - cell * 3;
    const float* t = target + (size_t)n * 6;
    const int poff = cell * 255 + a * 85;

    // ---- all loads unconditional, up-front (same cache lines either way) ----
    const float2 t01 = *reinterpret_cast<const float2*>(t);
    const float2 t23 = *reinterpret_cast<const float2*>(t + 2);
    const float2 t45 = *reinterpret_cast<const float2*>(t + 4);
    const f4v   pq = *reinterpret_cast<const f4v*>(pred + poff);  // p0..p3
    const float p4 = pred[poff + 4];
    const float p0 = pq.x, p1 = pq.y, p2 = pq.z, p3 = pq.w;
    const float aw = anchors[a * 2 + 0];
    const float ah = anchors[a * 2 + 1];

    const bool isobj   = (t01.x != 0.0f);
    const int  label_l = isobj ? (int)t45.y : 0;

    // ---- peel CE iteration 0: issue its gather before the box/IoU math ----
    unsigned long long m = __ballot(isobj);
    unsigned long long m2 = m;
    int b0 = -1, b1 = -1, b2 = -1, b3 = -1;
    if (m2) { b0 = __ffsll(m2) - 1; m2 &= m2 - 1; }
    if (m2) { b1 = __ffsll(m2) - 1; m2 &= m2 - 1; }
    if (m2) { b2 = __ffsll(m2) - 1; m2 &= m2 - 1; }
    if (m2) { b3 = __ffsll(m2) - 1; m2 &= m2 - 1; }
    int  src0 = (grp == 0) ? b0 : (grp == 1) ? b1 : (grp == 2) ? b2 : b3;
    bool act0 = (src0 >= 0);
    int  s0   = act0 ? src0 : 0;
    int  offu0  = __shfl(poff, s0, 64) + 5;
    int  label0 = __shfl(label_l, s0, 64);
    // interleaved-coalesced: 16 active lanes read CONSECUTIVE dwords per instr
    const float* cl0 = pred + offu0;
    float w0 = 0.f, w1 = 0.f, w2 = 0.f, w3 = 0.f, w4 = 0.f;
    if (act0) {
        w0 = cl0[l16];      w1 = cl0[l16 + 16]; w2 = cl0[l16 + 32];
        w3 = cl0[l16 + 48]; w4 = cl0[l16 + 64];
    }

    float s_bce = 0.f, s_ce = 0.f, s_sq = 0.f, s_objt = 0.f;

    // ---- per-anchor math (native transcendentals; abs tolerance 0.49) ----
    if (!isobj) {
        // softplus: log argument in (1,2] -> native log safe
        s_bce = fmaxf(p0, 0.0f) + __logf(1.0f + __expf(-fabsf(p0)));
    } else {
        float px = fast_rcp(1.0f + __expf(-p1));   // sigmoid
        float py = fast_rcp(1.0f + __expf(-p2));
        float tx = t01.y, ty = t23.x;
        float tw = __logf(1e-16f + t23.y * fast_rcp(aw));
        float th = __logf(1e-16f + t45.x * fast_rcp(ah));
        float dx = tx - px, dy = ty - py, dw = tw - p3, dh = th - p4;
        s_sq = dx * dx + dy * dy + dw * dw + dh * dh;

        // objectness MSE vs IoU (faithful reference quirk:
        // decoded pred box vs log-space target box)
        float bw = __expf(p3) * aw;
        float bh = __expf(p4) * ah;
        float b1x1 = px - bw * 0.5f, b1x2 = px + bw * 0.5f;
        float b1y1 = py - bh * 0.5f, b1y2 = py + bh * 0.5f;
        float b2x1 = tx - tw * 0.5f, b2x2 = tx + tw * 0.5f;
        float b2y1 = ty - th * 0.5f, b2y2 = ty + th * 0.5f;
        float iw = fmaxf(fminf(b1x2, b2x2) - fmaxf(b1x1, b2x1), 0.0f);
        float ih = fmaxf(fminf(b1y2, b2y2) - fmaxf(b1y1, b2y1), 0.0f);
        float inter = iw * ih;
        float a1 = fabsf((b1x2 - b1x1) * (b1y2 - b1y1));
        float a2 = fabsf((b2x2 - b2x1) * (b2y2 - b2y1));
        float iou = inter * fast_rcp(a1 + a2 - inter + 1e-6f);
        float d = iou - p0;
        s_objt = d * d;
    }

    // ---- finish CE iteration 0 (butterflies on 16-lane groups) ----
    if (m) {
        float mx = fmaxf(fmaxf(fmaxf(w0, w1), fmaxf(w2, w3)), w4);
        #pragma unroll
        for (int o = 8; o > 0; o >>= 1) mx = fmaxf(mx, __shfl_xor(mx, o, 16));

        float se = __expf(w0 - mx) + __expf(w1 - mx) + __expf(w2 - mx)
                 + __expf(w3 - mx) + __expf(w4 - mx);
        #pragma unroll
        for (int o = 8; o > 0; o >>= 1) se += __shfl_xor(se, o, 16);

        // class c lives in register r=c>>4 of lane c&15 (within the group)
        int r  = label0 >> 4;
        float cand = (r == 0) ? w0 : (r == 1) ? w1 : (r == 2) ? w2
                   : (r == 3) ? w3 : w4;
        float cll  = __shfl(cand, (grp << 4) + (label0 & 15), 64);

        if (act0 && l16 == 0) s_ce += (mx + __logf(se)) - cll;
    }

    // ---- remaining CE iterations (~20% of waves) ----
    while (m2) {
        int c0 = -1, c1 = -1, c2 = -1, c3 = -1;
        if (m2) { c0 = __ffsll(m2) - 1; m2 &= m2 - 1; }
        if (m2) { c1 = __ffsll(m2) - 1; m2 &= m2 - 1; }
        if (m2) { c2 = __ffsll(m2) - 1; m2 &= m2 - 1; }
        if (m2) { c3 = __ffsll(m2) - 1; m2 &= m2 - 1; }
        int src = (grp == 0) ? c0 : (grp == 1) ? c1 : (grp == 2) ? c2 : c3;
        bool active = (src >= 0);
        int s = active ? src : 0;
        int offu  = __shfl(poff, s, 64) + 5;
        int label = __shfl(label_l, s, 64);
        const float* cl = pred + offu;

        float v0 = 0.f, v1 = 0.f, v2 = 0.f, v3 = 0.f, v4 = 0.f;
        if (active) {
            v0 = cl[l16];      v1 = cl[l16 + 16]; v2 = cl[l16 + 32];
            v3 = cl[l16 + 48]; v4 = cl[l16 + 64];
        }

        float mx = fmaxf(fmaxf(fmaxf(v0, v1), fmaxf(v2, v3)), v4);
        #pragma unroll
        for (int o = 8; o > 0; o >>= 1) mx = fmaxf(mx, __shfl_xor(mx, o, 16));

        float se = __expf(v0 - mx) + __expf(v1 - mx) + __expf(v2 - mx)
                 + __expf(v3 - mx) + __expf(v4 - mx);
        #pragma unroll
        for (int o = 8; o > 0; o >>= 1) se += __shfl_xor(se, o, 16);

        int r  = label >> 4;
        float cand = (r == 0) ? v0 : (r == 1) ? v1 : (r == 2) ? v2
                   : (r == 3) ? v3 : v4;
        float cll  = __shfl(cand, (grp << 4) + (label & 15), 64);

        if (active && l16 == 0) s_ce += (mx + __logf(se)) - cll;
    }

    // ---- combine obj-side quantities (shared divisor n_obj):
    //      comb = ce + 2.5*sq + objt  ->  only 2 reduced floats per wave ----
    float s_comb = fmaf(2.5f, s_sq, s_objt) + s_ce;

    // obj count is free: popcount of the ballot (no shuffles needed)
    const float wave_nobj = (float)__popcll(m);

    // ---- wave-64 reduction: 2 quantities x 6 steps (was 26 shuffles) ----
    #pragma unroll
    for (int off = 32; off > 0; off >>= 1) {
        s_bce  += __shfl_down(s_bce,  off, 64);
        s_comb += __shfl_down(s_comb, off, 64);
    }

    // ---- block reduction through LDS; column-major partial write ----
    __shared__ float red[4][3];
    int wave = tid >> 6;
    if ((tid & 63) == 0) {
        red[wave][0] = wave_nobj; red[wave][1] = s_bce; red[wave][2] = s_comb;
    }
    __syncthreads();
    if (tid < 3) {
        float v = red[0][tid] + red[1][tid] + red[2][tid] + red[3][tid];
        ws[tid * WSCOL + blockIdx.x] = v;
    }
}

__global__ __launch_bounds__(256) void yolo_final(const float* __restrict__ ws,
                                                  float* __restrict__ out) {
    float acc[3] = {0.f, 0.f, 0.f};
    #pragma unroll
    for (int r = 0; r < 4; ++r) {
        int b = threadIdx.x + r * 256;
        if (b < NBLK) {
            #pragma unroll
            for (int k = 0; k < 3; ++k) acc[k] += ws[k * WSCOL + b];
        }
    }
    #pragma unroll
    for (int off = 32; off > 0; off >>= 1) {
        #pragma unroll
        for (int k = 0; k < 3; ++k) acc[k] += __shfl_down(acc[k], off, 64);
    }
    __shared__ float red[4][3];
    int wave = threadIdx.x >> 6;
    if ((threadIdx.x & 63) == 0) {
        #pragma unroll
        for (int k = 0; k < 3; ++k) red[wave][k] = acc[k];
    }
    __syncthreads();
    if (threadIdx.x == 0) {
        float t[3];
        #pragma unroll
        for (int k = 0; k < 3; ++k)
            t[k] = red[0][k] + red[1][k] + red[2][k] + red[3][k];
        float n_obj   = fmaxf(t[0], 1.0f);
        float n_noobj = fmaxf((float)N_ANCH - t[0], 1.0f);
        // total = 10*noobj/n_noobj + (ce + 2.5*sq + objt)/n_obj
        out[0] = 10.0f * t[1] / n_noobj + t[2] / n_obj;
    }
}

extern "C" void kernel_launch(void* const* d_in, const int* in_sizes, int n_in,
                              void* d_out, int out_size, void* d_ws, size_t ws_size,
                              hipStream_t stream) {
    const float* target  = (const float*)d_in[0];
    const float* pred    = (const float*)d_in[1];
    const float* anchors = (const float*)d_in[2];
    float* out = (float*)d_out;
    float* ws  = (float*)d_ws;

    hipLaunchKernelGGL(yolo_main, dim3(NBLK), dim3(BLOCK), 0, stream,
                       target, pred, anchors, ws);

    hipLaunchKernelGGL(yolo_final, dim3(1), dim3(256), 0, stream, ws, out);
}